// Round 1
// 118.582 us; speedup vs baseline: 1.2618x; 1.2618x over previous
//
#include <hip/hip_runtime.h>

#define KDIM 4096   // rows of x (= both i and j extents)
#define NDIM 1024   // feature dim
#define ALPHA 0.2f
#define LOG2E 1.4426950408889634f
#define CCH 256     // chunks over sorted rank axis
#define RCH 16      // ranks per chunk
#define PFL 256     // LDS-staged (F1,F2,rz) entries per block (fallback to global beyond)

// Persistent device scratch. All f32.
// Sorted-prefix decomposition: sort j by s2 desc (permutation sigma);
// sel(i,j) <=> rank(j) < t_i. h_i = [F1_i*A1[t_i] + F2_i*(A2tot-A2[t_i])] / Z_i.
__device__ __align__(16) float g_s1L[KDIM];
__device__ __align__(16) float g_s2L[KDIM];
__device__ __align__(16) float g_E [2 * KDIM];      // interleaved (E1_j, E2_j)
__device__ __align__(16) float g_F1[KDIM];
__device__ __align__(16) float g_F2[KDIM];
__device__ __align__(16) float g_rZ[KDIM];
__device__ __align__(16) int   g_t  [KDIM];         // t_i = #{j: s2_j >= -s1_i}
__device__ __align__(16) int   g_sig[KDIM];         // rank -> j
__device__ __align__(16) float g_cs [CCH][2 * NDIM];  // chunk sums   (S1 | S2)  2 MB
__device__ __align__(16) float g_pre[CCH][2 * NDIM];  // excl. prefix (S1 | S2)  2 MB
__device__ __align__(16) float g_tot[2 * NDIM];       // column totals

// ---- kernel 1: s1L/s2L = (x @ w1, x @ w2) * log2(e).  One wave per row. ----
__global__ __launch_bounds__(256) void k_dots(const float* __restrict__ x,
                                              const float* __restrict__ w){
  const int wid = threadIdx.x >> 6, lane = threadIdx.x & 63;
  const int row = blockIdx.x * 4 + wid;
  const float* xr = x + (size_t)row * NDIM;
  float d1 = 0.f, d2 = 0.f;
  #pragma unroll
  for (int q = 0; q < 4; ++q){
    const int off = q * 256 + lane * 4;
    float4 X  = *(const float4*)(xr + off);
    float4 W1 = *(const float4*)(w + off);
    float4 W2 = *(const float4*)(w + NDIM + off);
    d1 = fmaf(X.x, W1.x, fmaf(X.y, W1.y, fmaf(X.z, W1.z, fmaf(X.w, W1.w, d1))));
    d2 = fmaf(X.x, W2.x, fmaf(X.y, W2.y, fmaf(X.z, W2.z, fmaf(X.w, W2.w, d2))));
  }
  #pragma unroll
  for (int m = 32; m >= 1; m >>= 1){
    d1 += __shfl_xor(d1, m, 64);
    d2 += __shfl_xor(d2, m, 64);
  }
  if (lane == 0){
    g_s1L[row] = d1 * LOG2E;
    g_s2L[row] = d2 * LOG2E;
  }
}

// ---- kernel 2: m2 = max_j s2L; E1/E2 per j; F1/F2 per i. One block. ----
__global__ __launch_bounds__(1024) void k_escan(){
  __shared__ float red[1024];
  const int tid = threadIdx.x;
  const float4 s2v = *(const float4*)&g_s2L[tid * 4];
  red[tid] = fmaxf(fmaxf(s2v.x, s2v.y), fmaxf(s2v.z, s2v.w));
  __syncthreads();
  #pragma unroll
  for (int s = 512; s >= 1; s >>= 1){
    if (tid < s) red[tid] = fmaxf(red[tid], red[tid + s]);
    __syncthreads();
  }
  const float m2 = red[0];

  float4 e0, e1;
  e0.x = __builtin_amdgcn_exp2f(s2v.x); e0.y = __builtin_amdgcn_exp2f(ALPHA * s2v.x);
  e0.z = __builtin_amdgcn_exp2f(s2v.y); e0.w = __builtin_amdgcn_exp2f(ALPHA * s2v.y);
  e1.x = __builtin_amdgcn_exp2f(s2v.z); e1.y = __builtin_amdgcn_exp2f(ALPHA * s2v.z);
  e1.z = __builtin_amdgcn_exp2f(s2v.w); e1.w = __builtin_amdgcn_exp2f(ALPHA * s2v.w);
  *(float4*)&g_E[tid * 8]     = e0;
  *(float4*)&g_E[tid * 8 + 4] = e1;

  const float4 s1v = *(const float4*)&g_s1L[tid * 4];
  float4 F1, F2;
  {
    float t, mL;
    t = s1v.x + m2; mL = fmaxf(t, ALPHA * t);
    F1.x = __builtin_amdgcn_exp2f(s1v.x - mL);
    F2.x = __builtin_amdgcn_exp2f(fmaf(ALPHA, s1v.x, -mL));
    t = s1v.y + m2; mL = fmaxf(t, ALPHA * t);
    F1.y = __builtin_amdgcn_exp2f(s1v.y - mL);
    F2.y = __builtin_amdgcn_exp2f(fmaf(ALPHA, s1v.y, -mL));
    t = s1v.z + m2; mL = fmaxf(t, ALPHA * t);
    F1.z = __builtin_amdgcn_exp2f(s1v.z - mL);
    F2.z = __builtin_amdgcn_exp2f(fmaf(ALPHA, s1v.z, -mL));
    t = s1v.w + m2; mL = fmaxf(t, ALPHA * t);
    F1.w = __builtin_amdgcn_exp2f(s1v.w - mL);
    F2.w = __builtin_amdgcn_exp2f(fmaf(ALPHA, s1v.w, -mL));
  }
  *(float4*)&g_F1[tid * 4] = F1;
  *(float4*)&g_F2[tid * 4] = F2;
}

// ---- kernel 3: ranks (stable desc sort of s2L via counting) + t_i counts. ----
// 8192 outputs: o<4096 -> scatter g_sig[rank_o]=o ; o>=4096 -> g_t[o-4096]=t.
// Each block: 16 outputs x 16 j'-subranges of 256; s2L staged in LDS.
__global__ __launch_bounds__(256) void k_rank(){
  __shared__ __align__(16) float s2s[KDIM];    // 16 KB
  const int tid = threadIdx.x;
  #pragma unroll
  for (int q = 0; q < 4; ++q)
    ((float4*)s2s)[q * 256 + tid] = ((const float4*)g_s2L)[q * 256 + tid];
  __syncthreads();
  const int grp = tid >> 4, sub = tid & 15;
  const int o = blockIdx.x * 16 + grp;         // 0..8191
  int cnt = 0;
  if (o < KDIM){
    const float val = s2s[o];
    #pragma unroll 4
    for (int m = 0; m < 64; ++m){
      const int q4 = sub * 64 + ((m + sub) & 63);   // rotate: spread LDS banks
      const float4 v = ((const float4*)s2s)[q4];
      const int j0 = q4 * 4;
      cnt += (v.x > val || (v.x == val && (j0    ) < o));
      cnt += (v.y > val || (v.y == val && (j0 + 1) < o));
      cnt += (v.z > val || (v.z == val && (j0 + 2) < o));
      cnt += (v.w > val || (v.w == val && (j0 + 3) < o));
    }
  } else {
    const float thr = -g_s1L[o - KDIM];
    #pragma unroll 4
    for (int m = 0; m < 64; ++m){
      const int q4 = sub * 64 + ((m + sub) & 63);
      const float4 v = ((const float4*)s2s)[q4];
      cnt += (v.x >= thr) + (v.y >= thr) + (v.z >= thr) + (v.w >= thr);
    }
  }
  cnt += __shfl_xor(cnt, 1, 64); cnt += __shfl_xor(cnt, 2, 64);
  cnt += __shfl_xor(cnt, 4, 64); cnt += __shfl_xor(cnt, 8, 64);
  if (sub == 0){
    if (o < KDIM) g_sig[cnt] = o;
    else          g_t[o - KDIM] = cnt;
  }
}

// ---- kernel 4: scalar exclusive scans z1/z2 over sorted order + rZ_i. ----
__global__ __launch_bounds__(1024) void k_zscan(){
  __shared__ __align__(16) float z1L[KDIM + 1];
  __shared__ __align__(16) float z2L[KDIM + 1];
  __shared__ float wsum1[16], wsum2[16];
  const int tid = threadIdx.x, lane = tid & 63, wid = tid >> 6;
  float v1[4], v2[4];
  #pragma unroll
  for (int q = 0; q < 4; ++q){
    const int j = g_sig[tid * 4 + q];
    v1[q] = g_E[2 * j];
    v2[q] = g_E[2 * j + 1];
  }
  const float s1 = v1[0] + v1[1] + v1[2] + v1[3];
  const float s2 = v2[0] + v2[1] + v2[2] + v2[3];
  float i1 = s1, i2 = s2;
  #pragma unroll
  for (int d = 1; d < 64; d <<= 1){
    const float t1 = __shfl_up(i1, d, 64);
    const float t2 = __shfl_up(i2, d, 64);
    if (lane >= d){ i1 += t1; i2 += t2; }
  }
  if (lane == 63){ wsum1[wid] = i1; wsum2[wid] = i2; }
  __syncthreads();
  float w1 = 0.f, w2 = 0.f;
  for (int k = 0; k < wid; ++k){ w1 += wsum1[k]; w2 += wsum2[k]; }
  float e1 = w1 + i1 - s1;        // exclusive prefix at this thread's first elem
  float e2 = w2 + i2 - s2;
  #pragma unroll
  for (int q = 0; q < 4; ++q){
    z1L[tid * 4 + q] = e1; e1 += v1[q];
    z2L[tid * 4 + q] = e2; e2 += v2[q];
  }
  if (tid == 1023){ z1L[KDIM] = e1; z2L[KDIM] = e2; }
  __syncthreads();
  const float z2T = z2L[KDIM];
  #pragma unroll
  for (int q = 0; q < 4; ++q){
    const int i = q * 1024 + tid;
    const int t = g_t[i];
    const float Z = fmaf(g_F1[i], z1L[t], g_F2[i] * (z2T - z2L[t]));
    g_rZ[i] = 1.0f / Z;
  }
}

// ---- kernel 5: per-chunk vector sums S1_c = sum E1*x, S2_c = sum E2*x. ----
__global__ __launch_bounds__(256) void k_chunksum(const float* __restrict__ x){
  __shared__ int   js [RCH];
  __shared__ float e1s[RCH], e2s[RCH];
  const int c = blockIdx.x, tid = threadIdx.x;
  if (tid < RCH){
    const int j = g_sig[c * RCH + tid];
    js[tid]  = j;
    e1s[tid] = g_E[2 * j];
    e2s[tid] = g_E[2 * j + 1];
  }
  __syncthreads();
  float4 a1 = {0.f, 0.f, 0.f, 0.f}, a2 = {0.f, 0.f, 0.f, 0.f};
  #pragma unroll
  for (int r = 0; r < RCH; ++r){
    const float4 xv = *(const float4*)(x + (size_t)js[r] * NDIM + tid * 4);
    const float e1 = e1s[r], e2 = e2s[r];
    a1.x = fmaf(e1, xv.x, a1.x); a1.y = fmaf(e1, xv.y, a1.y);
    a1.z = fmaf(e1, xv.z, a1.z); a1.w = fmaf(e1, xv.w, a1.w);
    a2.x = fmaf(e2, xv.x, a2.x); a2.y = fmaf(e2, xv.y, a2.y);
    a2.z = fmaf(e2, xv.z, a2.z); a2.w = fmaf(e2, xv.w, a2.w);
  }
  *(float4*)&g_cs[c][tid * 4]        = a1;
  *(float4*)&g_cs[c][NDIM + tid * 4] = a2;
}

// ---- kernel 6: exclusive scan of chunk sums over c (per column) + totals. ----
// 64 blocks x 32 cols; 8 segments of 32 chunks per column.
__global__ __launch_bounds__(256) void k_chunkscan(){
  __shared__ float TL[CCH][32];   // 32 KB; bank = col -> conflict-free
  __shared__ float SS[8][32];
  const int tid = threadIdx.x;
  const int s = tid >> 5, k = tid & 31;
  const int col = blockIdx.x * 32 + k;
  float run = 0.f;
  #pragma unroll 8
  for (int m = 0; m < 32; ++m){
    const float v = g_cs[s * 32 + m][col];
    TL[s * 32 + m][k] = v;
    run += v;
  }
  SS[s][k] = run;
  __syncthreads();
  if (s == 0){
    float acc = 0.f;
    #pragma unroll
    for (int t = 0; t < 8; ++t){
      const float v = SS[t][k];
      SS[t][k] = acc;
      acc += v;
    }
    g_tot[col] = acc;
  }
  __syncthreads();
  run = SS[s][k];
  #pragma unroll 8
  for (int m = 0; m < 32; ++m){
    g_pre[s * 32 + m][col] = run;
    run += TL[s * 32 + m][k];
  }
}

// ---- kernel 7: fused in-chunk scan + emit. Block c walks its 16 sorted rows
// maintaining running prefix (a1,a2) from g_pre[c]; outputs i with t_i==rank
// are emitted just before adding that rank's row. Last block also emits t=4096.
__global__ __launch_bounds__(256) void k_emit(const float* __restrict__ x,
                                              float* __restrict__ out){
  __shared__ int    js [RCH];
  __shared__ float  e1s[RCH], e2s[RCH];
  __shared__ int    cnt[RCH + 1];
  __shared__ int    off[RCH + 2];
  __shared__ int    pos[RCH + 1];
  __shared__ int    ilist[KDIM];      // 16 KB (worst-case safe)
  __shared__ float4 pfl[PFL];         // staged (F1,F2,rz)
  const int c = blockIdx.x, tid = threadIdx.x;
  const bool last = (c == CCH - 1);
  const int nbuck = last ? RCH + 1 : RCH;   // bucket RCH only on last block (t=4096)
  if (tid < RCH){
    const int j = g_sig[c * RCH + tid];
    js[tid]  = j;
    e1s[tid] = g_E[2 * j];
    e2s[tid] = g_E[2 * j + 1];
  }
  if (tid <= RCH) cnt[tid] = 0;
  __syncthreads();

  const int tbase = c * RCH;
  int myi[16], myr[16];
  #pragma unroll
  for (int q = 0; q < 16; ++q){
    const int i = q * 256 + tid;
    const int t = g_t[i];
    const int r = t - tbase;
    const bool in = (r >= 0) && (r < nbuck);
    myi[q] = i;
    myr[q] = in ? r : -1;
    if (in) atomicAdd(&cnt[r], 1);
  }
  __syncthreads();
  if (tid == 0){
    int run = 0;
    #pragma unroll
    for (int r = 0; r <= RCH; ++r){
      const int v = cnt[r];
      off[r] = run; pos[r] = run;
      run += v;
    }
    off[RCH + 1] = run;
  }
  __syncthreads();
  #pragma unroll
  for (int q = 0; q < 16; ++q){
    if (myr[q] >= 0){
      const int p = atomicAdd(&pos[myr[q]], 1);
      ilist[p] = myi[q];
      if (p < PFL)
        pfl[p] = make_float4(g_F1[myi[q]], g_F2[myi[q]], g_rZ[myi[q]], 0.f);
    }
  }
  __syncthreads();

  float4 a1 = *(const float4*)&g_pre[c][tid * 4];
  float4 a2 = *(const float4*)&g_pre[c][NDIM + tid * 4];
  const float4 t2 = *(const float4*)&g_tot[NDIM + tid * 4];
  float4 v[RCH];
  #pragma unroll
  for (int r = 0; r < RCH; ++r)      // issue all 16 gathered row loads up front
    v[r] = *(const float4*)(x + (size_t)js[r] * NDIM + tid * 4);

  #pragma unroll
  for (int r = 0; r < RCH; ++r){
    // emit all i with t_i == tbase + r (prefix excludes row r)
    for (int e = off[r]; e < off[r + 1]; ++e){
      const int i = ilist[e];
      float F1, F2, rz;
      if (e < PFL){ const float4 pf = pfl[e]; F1 = pf.x; F2 = pf.y; rz = pf.z; }
      else        { F1 = g_F1[i]; F2 = g_F2[i]; rz = g_rZ[i]; }
      float4 h;
      h.x = fmaf(F1, a1.x, F2 * (t2.x - a2.x)) * rz;
      h.y = fmaf(F1, a1.y, F2 * (t2.y - a2.y)) * rz;
      h.z = fmaf(F1, a1.z, F2 * (t2.z - a2.z)) * rz;
      h.w = fmaf(F1, a1.w, F2 * (t2.w - a2.w)) * rz;
      *(float4*)(out + (size_t)i * NDIM + tid * 4) = h;
    }
    const float e1 = e1s[r], e2 = e2s[r];
    const float4 xv = v[r];
    a1.x = fmaf(e1, xv.x, a1.x); a1.y = fmaf(e1, xv.y, a1.y);
    a1.z = fmaf(e1, xv.z, a1.z); a1.w = fmaf(e1, xv.w, a1.w);
    a2.x = fmaf(e2, xv.x, a2.x); a2.y = fmaf(e2, xv.y, a2.y);
    a2.z = fmaf(e2, xv.z, a2.z); a2.w = fmaf(e2, xv.w, a2.w);
  }
  if (last){
    // t = 4096: fully-selected rows, prefix = totals
    for (int e = off[RCH]; e < off[RCH + 1]; ++e){
      const int i = ilist[e];
      float F1, F2, rz;
      if (e < PFL){ const float4 pf = pfl[e]; F1 = pf.x; F2 = pf.y; rz = pf.z; }
      else        { F1 = g_F1[i]; F2 = g_F2[i]; rz = g_rZ[i]; }
      float4 h;
      h.x = fmaf(F1, a1.x, F2 * (t2.x - a2.x)) * rz;
      h.y = fmaf(F1, a1.y, F2 * (t2.y - a2.y)) * rz;
      h.z = fmaf(F1, a1.z, F2 * (t2.z - a2.z)) * rz;
      h.w = fmaf(F1, a1.w, F2 * (t2.w - a2.w)) * rz;
      *(float4*)(out + (size_t)i * NDIM + tid * 4) = h;
    }
  }
}

extern "C" void kernel_launch(void* const* d_in, const int* in_sizes, int n_in,
                              void* d_out, int out_size, void* d_ws, size_t ws_size,
                              hipStream_t stream){
  const float* x = (const float*)d_in[0];   // f32 (4096x1024)
  const float* w = (const float*)d_in[1];   // f32 (2048)
  float* out = (float*)d_out;               // f32 (4096x1024)
  (void)in_sizes; (void)n_in; (void)out_size; (void)d_ws; (void)ws_size;

  k_dots     <<<dim3(1024), dim3(256),  0, stream>>>(x, w);
  k_escan    <<<dim3(1),    dim3(1024), 0, stream>>>();
  k_rank     <<<dim3(512),  dim3(256),  0, stream>>>();
  k_zscan    <<<dim3(1),    dim3(1024), 0, stream>>>();
  k_chunksum <<<dim3(CCH),  dim3(256),  0, stream>>>(x);
  k_chunkscan<<<dim3(64),   dim3(256),  0, stream>>>();
  k_emit     <<<dim3(CCH),  dim3(256),  0, stream>>>(x, out);
}

// Round 2
// 102.627 us; speedup vs baseline: 1.4579x; 1.1555x over previous
//
#include <hip/hip_runtime.h>

#define KDIM 4096   // rows of x (= both i and j extents)
#define NDIM 1024   // feature dim
#define ALPHA 0.2f
#define LOG2E 1.4426950408889634f
#define CCH 256     // chunks over sorted rank axis
#define RCH 16      // ranks per chunk
#define PFL 256     // LDS-staged (F1,F2) entries per block (fallback to global beyond)

// Sorted-prefix decomposition (exact): sort j by s2 desc (permutation sigma);
// sel(i,j) <=> rank(j) < t_i.
//   h_i = [F1_i*A1[t_i] + F2_i*(A2tot-A2[t_i])] / Z_i
//   Z_i =  F1_i*z1[t_i] + F2_i*(z2tot-z2[t_i])
// No max-shift needed: the per-row stabilizer cancels between numerator and Z,
// and |s1+s2| is far from f32 overflow. So E/F are row-local (fused into k_dots).
__device__ __align__(16) float g_s1L[KDIM];
__device__ __align__(16) float g_s2L[KDIM];
__device__ __align__(16) float g_E [2 * KDIM];        // interleaved (E1_j, E2_j)
__device__ __align__(16) float g_F1[KDIM];
__device__ __align__(16) float g_F2[KDIM];
__device__ __align__(16) int   g_t  [KDIM];           // t_i = #{j: s2_j >= -s1_i}
__device__ __align__(16) int   g_sig[KDIM];           // rank -> j
__device__ __align__(16) float g_cs [CCH][2 * NDIM];  // chunk sums   (S1 | S2)  2 MB
__device__ __align__(16) float g_pre[CCH][2 * NDIM];  // excl. prefix (S1 | S2)  2 MB
__device__ __align__(16) float g_tot[2 * NDIM];       // column totals
__device__ __align__(16) float g_cz [2 * CCH];        // scalar chunk sums (z1,z2)
__device__ __align__(16) float g_zpre[2 * CCH];       // scalar excl. prefix
__device__ __align__(16) float g_ztot[2];             // scalar totals

// ---- kernel 1: s1L/s2L = (x @ w1, x @ w2) * log2(e); E/F per row. ----
// One wave per row. E1=2^s2, E2=2^(a*s2), F1=2^s1, F2=2^(a*s1).
__global__ __launch_bounds__(256) void k_dots(const float* __restrict__ x,
                                              const float* __restrict__ w){
  const int wid = threadIdx.x >> 6, lane = threadIdx.x & 63;
  const int row = blockIdx.x * 4 + wid;
  const float* xr = x + (size_t)row * NDIM;
  float d1 = 0.f, d2 = 0.f;
  #pragma unroll
  for (int q = 0; q < 4; ++q){
    const int off = q * 256 + lane * 4;
    float4 X  = *(const float4*)(xr + off);
    float4 W1 = *(const float4*)(w + off);
    float4 W2 = *(const float4*)(w + NDIM + off);
    d1 = fmaf(X.x, W1.x, fmaf(X.y, W1.y, fmaf(X.z, W1.z, fmaf(X.w, W1.w, d1))));
    d2 = fmaf(X.x, W2.x, fmaf(X.y, W2.y, fmaf(X.z, W2.z, fmaf(X.w, W2.w, d2))));
  }
  #pragma unroll
  for (int m = 32; m >= 1; m >>= 1){
    d1 += __shfl_xor(d1, m, 64);
    d2 += __shfl_xor(d2, m, 64);
  }
  if (lane == 0){
    const float s1 = d1 * LOG2E, s2 = d2 * LOG2E;
    g_s1L[row] = s1;
    g_s2L[row] = s2;
    g_E[2 * row]     = __builtin_amdgcn_exp2f(s2);
    g_E[2 * row + 1] = __builtin_amdgcn_exp2f(ALPHA * s2);
    g_F1[row] = __builtin_amdgcn_exp2f(s1);
    g_F2[row] = __builtin_amdgcn_exp2f(ALPHA * s1);
  }
}

// ---- kernel 2: ranks (stable desc sort of s2L via counting) + t_i counts. ----
// 8192 outputs: o<4096 -> scatter g_sig[rank_o]=o ; o>=4096 -> g_t[o-4096]=t.
// Each block: 16 outputs x 16 strided j'-subsets; s2L staged in LDS.
// q4 = m*16+sub: same-m reads are 16 consecutive float4 broadcast across the
// 4 output-groups of a wave -> 2-way bank aliasing only (free).
__global__ __launch_bounds__(256) void k_rank(){
  __shared__ __align__(16) float s2s[KDIM];    // 16 KB
  const int tid = threadIdx.x;
  #pragma unroll
  for (int q = 0; q < 4; ++q)
    ((float4*)s2s)[q * 256 + tid] = ((const float4*)g_s2L)[q * 256 + tid];
  __syncthreads();
  const int grp = tid >> 4, sub = tid & 15;
  const int o = blockIdx.x * 16 + grp;         // 0..8191
  int cnt = 0;
  if (o < KDIM){
    const float val = s2s[o];
    #pragma unroll 4
    for (int m = 0; m < 64; ++m){
      const int q4 = m * 16 + sub;
      const float4 v = ((const float4*)s2s)[q4];
      const int j0 = q4 * 4;
      cnt += (v.x > val || (v.x == val && (j0    ) < o));
      cnt += (v.y > val || (v.y == val && (j0 + 1) < o));
      cnt += (v.z > val || (v.z == val && (j0 + 2) < o));
      cnt += (v.w > val || (v.w == val && (j0 + 3) < o));
    }
  } else {
    const float thr = -g_s1L[o - KDIM];
    #pragma unroll 4
    for (int m = 0; m < 64; ++m){
      const int q4 = m * 16 + sub;
      const float4 v = ((const float4*)s2s)[q4];
      cnt += (v.x >= thr) + (v.y >= thr) + (v.z >= thr) + (v.w >= thr);
    }
  }
  cnt += __shfl_xor(cnt, 1, 64); cnt += __shfl_xor(cnt, 2, 64);
  cnt += __shfl_xor(cnt, 4, 64); cnt += __shfl_xor(cnt, 8, 64);
  if (sub == 0){
    if (o < KDIM) g_sig[cnt] = o;
    else          g_t[o - KDIM] = cnt;
  }
}

// ---- kernel 3: per-chunk vector sums S1_c = sum E1*x, S2_c = sum E2*x,
//      plus scalar chunk sums (sum E1, sum E2). ----
__global__ __launch_bounds__(256) void k_chunksum(const float* __restrict__ x){
  __shared__ int   js [RCH];
  __shared__ float e1s[RCH], e2s[RCH];
  const int c = blockIdx.x, tid = threadIdx.x;
  if (tid < RCH){
    const int j = g_sig[c * RCH + tid];
    js[tid]  = j;
    e1s[tid] = g_E[2 * j];
    e2s[tid] = g_E[2 * j + 1];
  }
  __syncthreads();
  if (tid == 0){
    float a = 0.f, b = 0.f;
    #pragma unroll
    for (int r = 0; r < RCH; ++r){ a += e1s[r]; b += e2s[r]; }
    g_cz[2 * c] = a; g_cz[2 * c + 1] = b;
  }
  float4 a1 = {0.f, 0.f, 0.f, 0.f}, a2 = {0.f, 0.f, 0.f, 0.f};
  #pragma unroll
  for (int r = 0; r < RCH; ++r){
    const float4 xv = *(const float4*)(x + (size_t)js[r] * NDIM + tid * 4);
    const float e1 = e1s[r], e2 = e2s[r];
    a1.x = fmaf(e1, xv.x, a1.x); a1.y = fmaf(e1, xv.y, a1.y);
    a1.z = fmaf(e1, xv.z, a1.z); a1.w = fmaf(e1, xv.w, a1.w);
    a2.x = fmaf(e2, xv.x, a2.x); a2.y = fmaf(e2, xv.y, a2.y);
    a2.z = fmaf(e2, xv.z, a2.z); a2.w = fmaf(e2, xv.w, a2.w);
  }
  *(float4*)&g_cs[c][tid * 4]        = a1;
  *(float4*)&g_cs[c][NDIM + tid * 4] = a2;
}

// ---- kernel 4: exclusive scan of chunk sums over c (per column) + totals,
//      plus scalar z1/z2 chunk scan (block 0, wave 0). ----
__global__ __launch_bounds__(256) void k_chunkscan(){
  __shared__ float TL[CCH][32];   // 32 KB; bank = col -> conflict-free
  __shared__ float SS[8][32];
  const int tid = threadIdx.x;
  const int s = tid >> 5, k = tid & 31;
  const int col = blockIdx.x * 32 + k;
  float run = 0.f;
  #pragma unroll 8
  for (int m = 0; m < 32; ++m){
    const float v = g_cs[s * 32 + m][col];
    TL[s * 32 + m][k] = v;
    run += v;
  }
  SS[s][k] = run;
  __syncthreads();
  if (s == 0){
    float acc = 0.f;
    #pragma unroll
    for (int t = 0; t < 8; ++t){
      const float v = SS[t][k];
      SS[t][k] = acc;
      acc += v;
    }
    g_tot[col] = acc;
  }
  __syncthreads();
  run = SS[s][k];
  #pragma unroll 8
  for (int m = 0; m < 32; ++m){
    g_pre[s * 32 + m][col] = run;
    run += TL[s * 32 + m][k];
  }
  if (blockIdx.x == 0 && tid < 64){
    float v1[4], v2[4];
    #pragma unroll
    for (int q = 0; q < 4; ++q){
      v1[q] = g_cz[2 * (tid * 4 + q)];
      v2[q] = g_cz[2 * (tid * 4 + q) + 1];
    }
    const float s1 = v1[0] + v1[1] + v1[2] + v1[3];
    const float s2 = v2[0] + v2[1] + v2[2] + v2[3];
    float i1 = s1, i2 = s2;
    #pragma unroll
    for (int d = 1; d < 64; d <<= 1){
      const float t1 = __shfl_up(i1, d, 64);
      const float t2 = __shfl_up(i2, d, 64);
      if (tid >= d){ i1 += t1; i2 += t2; }
    }
    float e1 = i1 - s1, e2 = i2 - s2;
    #pragma unroll
    for (int q = 0; q < 4; ++q){
      g_zpre[2 * (tid * 4 + q)]     = e1;
      g_zpre[2 * (tid * 4 + q) + 1] = e2;
      e1 += v1[q]; e2 += v2[q];
    }
    if (tid == 63){ g_ztot[0] = e1; g_ztot[1] = e2; }
  }
}

// ---- kernel 5: fused in-chunk scan + emit (Z inline). Block c walks its 16
// sorted rows maintaining vector prefix (a1,a2) from g_pre[c] AND scalar
// prefix (za1,za2) from g_zpre[c]; outputs i with t_i==rank are emitted just
// before adding that rank's row. Last block also emits t=4096.
__global__ __launch_bounds__(256) void k_emit(const float* __restrict__ x,
                                              float* __restrict__ out){
  __shared__ int    js [RCH];
  __shared__ float  e1s[RCH], e2s[RCH];
  __shared__ int    cnt[RCH + 1];
  __shared__ int    off[RCH + 2];
  __shared__ int    pos[RCH + 1];
  __shared__ int    ilist[KDIM];      // 16 KB (worst-case safe)
  __shared__ float2 pfl[PFL];         // staged (F1,F2)
  const int c = blockIdx.x, tid = threadIdx.x;
  const bool last = (c == CCH - 1);
  const int nbuck = last ? RCH + 1 : RCH;   // bucket RCH only on last block (t=4096)
  if (tid < RCH){
    const int j = g_sig[c * RCH + tid];
    js[tid]  = j;
    e1s[tid] = g_E[2 * j];
    e2s[tid] = g_E[2 * j + 1];
  }
  if (tid <= RCH) cnt[tid] = 0;
  __syncthreads();

  const int tbase = c * RCH;
  int myi[16], myr[16];
  #pragma unroll
  for (int q = 0; q < 16; ++q){
    const int i = q * 256 + tid;
    const int t = g_t[i];
    const int r = t - tbase;
    const bool in = (r >= 0) && (r < nbuck);
    myi[q] = i;
    myr[q] = in ? r : -1;
    if (in) atomicAdd(&cnt[r], 1);
  }
  __syncthreads();
  if (tid == 0){
    int run = 0;
    #pragma unroll
    for (int r = 0; r <= RCH; ++r){
      const int v = cnt[r];
      off[r] = run; pos[r] = run;
      run += v;
    }
    off[RCH + 1] = run;
  }
  __syncthreads();
  #pragma unroll
  for (int q = 0; q < 16; ++q){
    if (myr[q] >= 0){
      const int p = atomicAdd(&pos[myr[q]], 1);
      ilist[p] = myi[q];
      if (p < PFL)
        pfl[p] = make_float2(g_F1[myi[q]], g_F2[myi[q]]);
    }
  }
  __syncthreads();

  float4 a1 = *(const float4*)&g_pre[c][tid * 4];
  float4 a2 = *(const float4*)&g_pre[c][NDIM + tid * 4];
  const float4 t2 = *(const float4*)&g_tot[NDIM + tid * 4];
  float za1 = g_zpre[2 * c], za2 = g_zpre[2 * c + 1];
  const float zt2 = g_ztot[1];
  float4 v[RCH];
  #pragma unroll
  for (int r = 0; r < RCH; ++r)      // issue all 16 gathered row loads up front
    v[r] = *(const float4*)(x + (size_t)js[r] * NDIM + tid * 4);

  #pragma unroll
  for (int r = 0; r < RCH; ++r){
    // emit all i with t_i == tbase + r (prefix excludes row r)
    for (int e = off[r]; e < off[r + 1]; ++e){
      const int i = ilist[e];
      float F1, F2;
      if (e < PFL){ const float2 pf = pfl[e]; F1 = pf.x; F2 = pf.y; }
      else        { F1 = g_F1[i]; F2 = g_F2[i]; }
      const float rz = 1.0f / fmaf(F1, za1, F2 * (zt2 - za2));
      float4 h;
      h.x = fmaf(F1, a1.x, F2 * (t2.x - a2.x)) * rz;
      h.y = fmaf(F1, a1.y, F2 * (t2.y - a2.y)) * rz;
      h.z = fmaf(F1, a1.z, F2 * (t2.z - a2.z)) * rz;
      h.w = fmaf(F1, a1.w, F2 * (t2.w - a2.w)) * rz;
      *(float4*)(out + (size_t)i * NDIM + tid * 4) = h;
    }
    const float e1 = e1s[r], e2 = e2s[r];
    za1 += e1; za2 += e2;
    const float4 xv = v[r];
    a1.x = fmaf(e1, xv.x, a1.x); a1.y = fmaf(e1, xv.y, a1.y);
    a1.z = fmaf(e1, xv.z, a1.z); a1.w = fmaf(e1, xv.w, a1.w);
    a2.x = fmaf(e2, xv.x, a2.x); a2.y = fmaf(e2, xv.y, a2.y);
    a2.z = fmaf(e2, xv.z, a2.z); a2.w = fmaf(e2, xv.w, a2.w);
  }
  if (last){
    // t = 4096: fully-selected rows, prefix = totals
    for (int e = off[RCH]; e < off[RCH + 1]; ++e){
      const int i = ilist[e];
      float F1, F2;
      if (e < PFL){ const float2 pf = pfl[e]; F1 = pf.x; F2 = pf.y; }
      else        { F1 = g_F1[i]; F2 = g_F2[i]; }
      const float rz = 1.0f / fmaf(F1, za1, F2 * (zt2 - za2));
      float4 h;
      h.x = fmaf(F1, a1.x, F2 * (t2.x - a2.x)) * rz;
      h.y = fmaf(F1, a1.y, F2 * (t2.y - a2.y)) * rz;
      h.z = fmaf(F1, a1.z, F2 * (t2.z - a2.z)) * rz;
      h.w = fmaf(F1, a1.w, F2 * (t2.w - a2.w)) * rz;
      *(float4*)(out + (size_t)i * NDIM + tid * 4) = h;
    }
  }
}

extern "C" void kernel_launch(void* const* d_in, const int* in_sizes, int n_in,
                              void* d_out, int out_size, void* d_ws, size_t ws_size,
                              hipStream_t stream){
  const float* x = (const float*)d_in[0];   // f32 (4096x1024)
  const float* w = (const float*)d_in[1];   // f32 (2048)
  float* out = (float*)d_out;               // f32 (4096x1024)
  (void)in_sizes; (void)n_in; (void)out_size; (void)d_ws; (void)ws_size;

  k_dots     <<<dim3(1024), dim3(256), 0, stream>>>(x, w);
  k_rank     <<<dim3(512),  dim3(256), 0, stream>>>();
  k_chunksum <<<dim3(CCH),  dim3(256), 0, stream>>>(x);
  k_chunkscan<<<dim3(64),   dim3(256), 0, stream>>>();
  k_emit     <<<dim3(CCH),  dim3(256), 0, stream>>>(x, out);
}